// Round 1
// baseline (607.928 us; speedup 1.0000x reference)
//
#include <hip/hip_runtime.h>
#include <math.h>

#define T_  4
#define B_  16
#define C_  384
#define HW_ 256
#define E_  8
#define P_  32      // pixels per expert-block tile
#define PT_ 8       // HW_/P_

// taus = jnp.linspace(1.5, 4.0, 8) in fp32, endpoint exact
__device__ __forceinline__ float tau_of(int e) {
    if (e == 7) return 4.0f;
    const float delta = 2.5f / 7.0f;          // fp32 correctly-rounded constant
    return __fadd_rn(1.5f, __fmul_rn((float)e, delta));
}

// ---------------- Kernel 1: router LIF (tau=2) + exact spike mean over HW ----
// grid: B_*C_ blocks, 256 threads (one per pixel). m[t][b][c] = popcount/256 (exact).
__global__ __launch_bounds__(256) void k_router_lif(const float* __restrict__ x,
                                                    float* __restrict__ m) {
    int bc = blockIdx.x;
    int b = bc / C_, c = bc % C_;
    int p = threadIdx.x;
    int wv = threadIdx.x >> 6;
    __shared__ int cnt[T_][4];
    float v = 0.0f;
#pragma unroll
    for (int t = 0; t < T_; ++t) {
        float xv = x[((t * B_ + b) * C_ + c) * HW_ + p];
        v = __fadd_rn(v, __fdiv_rn(__fsub_rn(xv, v), 2.0f));
        bool s = (__fsub_rn(v, 1.0f) >= 0.0f);
        if (s) v = 0.0f;
        unsigned long long mask = __ballot(s);
        if ((threadIdx.x & 63) == 0) cnt[t][wv] = (int)__popcll(mask);
    }
    __syncthreads();
    if (threadIdx.x < T_) {
        int t = threadIdx.x;
        int tot = cnt[t][0] + cnt[t][1] + cnt[t][2] + cnt[t][3];
        m[(t * B_ + b) * C_ + c] = (float)tot * 0.00390625f;   // /256 exact
    }
}

// ---------------- Kernel 2: logits -> softmax -> top2 -> compacted slots -----
// grid: B_ blocks, 64 threads. Writes wslot[b*2+r] (weights) and eslot[b*2+r] (expert ids).
__global__ __launch_bounds__(64) void k_router_route(const float* __restrict__ m,
        const float* __restrict__ rW, const float* __restrict__ rb,
        const float* __restrict__ rbs, const float* __restrict__ rbb,
        float* __restrict__ wslot, int* __restrict__ eslot) {
    int b = blockIdx.x;
    int tid = threadIdx.x;
    int combo = tid & 31, half = tid >> 5;
    int e = combo >> 2, t = combo & 3;
    float dot = 0.0f;
    int c0 = half * 192;
    for (int c = 0; c < 192; ++c)
        dot = fmaf(rW[e * C_ + c0 + c], m[(t * B_ + b) * C_ + c0 + c], dot);
    dot += __shfl_down(dot, 32);   // lanes 0..31 now hold full dot for (e,t)
    float denom = sqrtf(__fadd_rn(1.0f, 1e-5f));
    float Ar = __fdiv_rn(rbs[e], denom);
    float lt = __fadd_rn(__fmul_rn(__fadd_rn(dot, rb[e]), Ar), rbb[e]);
    // sum over t within each e-group of 4 lanes
    lt = __fadd_rn(lt, __shfl_xor(lt, 1));
    lt = __fadd_rn(lt, __shfl_xor(lt, 2));
    __shared__ float lg[E_];
    if (half == 0 && t == 0) lg[e] = __fmul_rn(lt, 0.25f);     // mean over T
    __syncthreads();
    if (tid == 0) {
        float pr[E_];
        float mx = lg[0];
        for (int i = 1; i < E_; ++i) mx = fmaxf(mx, lg[i]);
        float s = 0.0f;
        for (int i = 0; i < E_; ++i) { pr[i] = expf(__fsub_rn(lg[i], mx)); s = __fadd_rn(s, pr[i]); }
        for (int i = 0; i < E_; ++i) pr[i] = __fdiv_rn(pr[i], s);
        int i0 = 0;
        for (int i = 1; i < E_; ++i) if (pr[i] > pr[i0]) i0 = i;     // stable: strict >
        int i1 = (i0 == 0) ? 1 : 0;
        for (int i = 0; i < E_; ++i) if (i != i0 && pr[i] > pr[i1]) i1 = i;
        float s2 = __fadd_rn(pr[i0], pr[i1]);
        wslot[b * 2 + 0] = __fdiv_rn(pr[i0], s2);
        wslot[b * 2 + 1] = __fdiv_rn(pr[i1], s2);
        eslot[b * 2 + 0] = i0;
        eslot[b * 2 + 1] = i1;
    }
}

// ---------------- Kernel 3: fused expert ------------------------------------
// grid: 32 slots * PT_ tiles = 256 blocks, 256 threads.
// Per block: LIF1 -> s1 bytes (LDS) -> conv1(N-chunks, K-tiles via LDS W) ->
// h -> identity atomicAdd + LIF2(regs) -> s2 bytes -> conv2 -> atomicAdd.
#define ACC8(t, sv)                                  \
    acc[t][0] = fmaf(sv, wa.x,  acc[t][0]);          \
    acc[t][1] = fmaf(sv, wa.y,  acc[t][1]);          \
    acc[t][2] = fmaf(sv, wa.z,  acc[t][2]);          \
    acc[t][3] = fmaf(sv, wa.w,  acc[t][3]);          \
    acc[t][4] = fmaf(sv, wb4.x, acc[t][4]);          \
    acc[t][5] = fmaf(sv, wb4.y, acc[t][5]);          \
    acc[t][6] = fmaf(sv, wb4.z, acc[t][6]);          \
    acc[t][7] = fmaf(sv, wb4.w, acc[t][7]);

__global__ __launch_bounds__(256) void k_expert(
        const float* __restrict__ x,
        const float* __restrict__ W1, const float* __restrict__ b1,
        const float* __restrict__ s1sc, const float* __restrict__ s1bi,
        const float* __restrict__ W2, const float* __restrict__ b2,
        const float* __restrict__ s2sc, const float* __restrict__ s2bi,
        const float* __restrict__ wslot, const int* __restrict__ eslot,
        float* __restrict__ out) {
    int blk = blockIdx.x;
    int ptile = blk & 7;
    int slot = blk >> 3;            // 0..31
    int b = slot >> 1;
    int rank = slot & 1;
    int e = eslot[b * 2 + rank];
    float wgt = wslot[b * 2 + rank];

    __shared__ float A1s[C_], B1s[C_], BB1s[C_], A2s[C_], B2s[C_], BB2s[C_];
    __shared__ unsigned char s1b[C_ * P_];
    __shared__ unsigned char s2b[C_ * P_];
    __shared__ __align__(16) float Wt[64 * 68];   // K-tile 64 x N-chunk 64, pad 68 (16B aligned rows)

    int tid = threadIdx.x;
    float denom = sqrtf(__fadd_rn(1.0f, 1e-5f));
    for (int o = tid; o < C_; o += 256) {
        A1s[o] = __fdiv_rn(s1sc[e * C_ + o], denom);
        B1s[o] = b1[e * C_ + o];
        BB1s[o] = s1bi[e * C_ + o];
        A2s[o] = __fdiv_rn(s2sc[e * C_ + o], denom);
        B2s[o] = b2[e * C_ + o];
        BB2s[o] = s2bi[e * C_ + o];
    }

    float tau = tau_of(e);
    int pbase = ptile * P_;

    // ---- phase 1: LIF1 spikes as bytes (bit t of byte = spike at time t), 4 pixels/thread
    for (int idx = tid; idx < C_ * P_ / 4; idx += 256) {   // 3072 groups, 12 iters
        int c = idx >> 3;
        int q = (idx & 7) * 4;
        int p = pbase + q;
        float v0 = 0.f, v1 = 0.f, v2 = 0.f, v3 = 0.f;
        unsigned pack = 0;
#pragma unroll
        for (int t = 0; t < T_; ++t) {
            const float4 xv = *reinterpret_cast<const float4*>(&x[((t * B_ + b) * C_ + c) * HW_ + p]);
            v0 = __fadd_rn(v0, __fdiv_rn(__fsub_rn(xv.x, v0), tau));
            v1 = __fadd_rn(v1, __fdiv_rn(__fsub_rn(xv.y, v1), tau));
            v2 = __fadd_rn(v2, __fdiv_rn(__fsub_rn(xv.z, v2), tau));
            v3 = __fadd_rn(v3, __fdiv_rn(__fsub_rn(xv.w, v3), tau));
            if (__fsub_rn(v0, 1.0f) >= 0.0f) { pack |= (1u << t);        v0 = 0.f; }
            if (__fsub_rn(v1, 1.0f) >= 0.0f) { pack |= (1u << t) << 8;   v1 = 0.f; }
            if (__fsub_rn(v2, 1.0f) >= 0.0f) { pack |= (1u << t) << 16;  v2 = 0.f; }
            if (__fsub_rn(v3, 1.0f) >= 0.0f) { pack |= (1u << t) << 24;  v3 = 0.f; }
        }
        *reinterpret_cast<unsigned*>(&s1b[c * P_ + q]) = pack;
    }

    int lane = tid & 63, wv = tid >> 6;
    int og = lane >> 5, p0 = lane & 31;
    int p = pbase + p0;
    int oloc = (wv * 2 + og) * 8;         // 8 contiguous out-channels per thread

    // ---- pass A: conv1 + BN + residual + identity-out + LIF2 ----
    for (int n = 0; n < 6; ++n) {
        float acc[T_][8];
#pragma unroll
        for (int t = 0; t < T_; ++t)
#pragma unroll
            for (int j = 0; j < 8; ++j) acc[t][j] = 0.0f;
        int obase = n * 64 + oloc;
        for (int kt = 0; kt < 6; ++kt) {
            __syncthreads();
            for (int i = tid; i < 64 * 64; i += 256) {
                int o_ = i >> 6, c_ = i & 63;
                Wt[c_ * 68 + o_] = W1[(e * C_ + n * 64 + o_) * C_ + kt * 64 + c_];
            }
            __syncthreads();
            const unsigned char* sp = s1b + kt * 64 * P_ + p0;
            const float* wbase = Wt + oloc;
            for (int c = 0; c < 64; ++c) {
                const float4* wr = reinterpret_cast<const float4*>(wbase + c * 68);
                float4 wa = wr[0], wb4 = wr[1];
                unsigned sbyte = sp[c * P_];
                float sv0 = (float)(sbyte & 1u);
                float sv1 = (float)((sbyte >> 1) & 1u);
                float sv2 = (float)((sbyte >> 2) & 1u);
                float sv3 = (float)((sbyte >> 3) & 1u);
                ACC8(0, sv0) ACC8(1, sv1) ACC8(2, sv2) ACC8(3, sv3)
            }
        }
        // epilogue: h = x + (y1 + b1)*A1 + bb1 ; identity out ; LIF2 ; s2 bytes
#pragma unroll
        for (int j = 0; j < 8; ++j) {
            int o = obase + j;
            float a1 = A1s[o], bv = B1s[o], bbv = BB1s[o];
            float v2s = 0.0f;
            unsigned byte2 = 0;
#pragma unroll
            for (int t = 0; t < T_; ++t) {
                float xv = x[((t * B_ + b) * C_ + o) * HW_ + p];
                float h = __fadd_rn(xv, __fadd_rn(__fmul_rn(__fadd_rn(acc[t][j], bv), a1), bbv));
                atomicAdd(&out[((t * B_ + b) * C_ + o) * HW_ + p], wgt * h);
                v2s = __fadd_rn(v2s, __fdiv_rn(__fsub_rn(h, v2s), tau));
                if (__fsub_rn(v2s, 1.0f) >= 0.0f) { byte2 |= (1u << t); v2s = 0.0f; }
            }
            s2b[o * P_ + p0] = (unsigned char)byte2;
        }
    }

    // ---- pass B: conv2 + BN + weighted atomic out ----
    for (int n = 0; n < 6; ++n) {
        float acc[T_][8];
#pragma unroll
        for (int t = 0; t < T_; ++t)
#pragma unroll
            for (int j = 0; j < 8; ++j) acc[t][j] = 0.0f;
        int obase = n * 64 + oloc;
        for (int kt = 0; kt < 6; ++kt) {
            __syncthreads();
            for (int i = tid; i < 64 * 64; i += 256) {
                int o_ = i >> 6, c_ = i & 63;
                Wt[c_ * 68 + o_] = W2[(e * C_ + n * 64 + o_) * C_ + kt * 64 + c_];
            }
            __syncthreads();
            const unsigned char* sp = s2b + kt * 64 * P_ + p0;
            const float* wbase = Wt + oloc;
            for (int c = 0; c < 64; ++c) {
                const float4* wr = reinterpret_cast<const float4*>(wbase + c * 68);
                float4 wa = wr[0], wb4 = wr[1];
                unsigned sbyte = sp[c * P_];
                float sv0 = (float)(sbyte & 1u);
                float sv1 = (float)((sbyte >> 1) & 1u);
                float sv2 = (float)((sbyte >> 2) & 1u);
                float sv3 = (float)((sbyte >> 3) & 1u);
                ACC8(0, sv0) ACC8(1, sv1) ACC8(2, sv2) ACC8(3, sv3)
            }
        }
#pragma unroll
        for (int j = 0; j < 8; ++j) {
            int o = obase + j;
            float a2 = A2s[o], bv = B2s[o], bbv = BB2s[o];
#pragma unroll
            for (int t = 0; t < T_; ++t) {
                float val = wgt * __fadd_rn(__fmul_rn(__fadd_rn(acc[t][j], bv), a2), bbv);
                atomicAdd(&out[((t * B_ + b) * C_ + o) * HW_ + p], val);
            }
        }
    }
}

extern "C" void kernel_launch(void* const* d_in, const int* in_sizes, int n_in,
                              void* d_out, int out_size, void* d_ws, size_t ws_size,
                              hipStream_t stream) {
    const float* x    = (const float*)d_in[0];
    const float* rW   = (const float*)d_in[1];
    const float* rb   = (const float*)d_in[2];
    const float* rbs  = (const float*)d_in[3];
    const float* rbb  = (const float*)d_in[4];
    const float* W1   = (const float*)d_in[5];
    const float* b1   = (const float*)d_in[6];
    const float* s1sc = (const float*)d_in[7];
    const float* s1bi = (const float*)d_in[8];
    const float* W2   = (const float*)d_in[9];
    const float* b2   = (const float*)d_in[10];
    const float* s2sc = (const float*)d_in[11];
    const float* s2bi = (const float*)d_in[12];
    float* out = (float*)d_out;

    float* wsf   = (float*)d_ws;
    float* wslot = wsf;                    // 32 floats
    int*   eslot = (int*)(wsf + 32);       // 32 ints
    float* m     = wsf + 64;               // T_*B_*C_ = 24576 floats

    hipMemsetAsync(d_out, 0, (size_t)out_size * sizeof(float), stream);
    hipLaunchKernelGGL(k_router_lif, dim3(B_ * C_), dim3(256), 0, stream, x, m);
    hipLaunchKernelGGL(k_router_route, dim3(B_), dim3(64), 0, stream,
                       m, rW, rb, rbs, rbb, wslot, eslot);
    hipLaunchKernelGGL(k_expert, dim3(32 * PT_), dim3(256), 0, stream,
                       x, W1, b1, s1sc, s1bi, W2, b2, s2sc, s2bi, wslot, eslot, out);
}

// Round 2
// 466.438 us; speedup vs baseline: 1.3033x; 1.3033x over previous
//
#include <hip/hip_runtime.h>
#include <math.h>

#define T_    4
#define B_    16
#define C_    384
#define HW_   256
#define E_    8
#define P_    32      // pixels per expert-block tile
#define PT_   8       // HW_/P_
#define TH_   512     // threads per expert block
#define NC_   128     // N-chunk (output channels per chunk)
#define KT_   128     // K-tile (input channels per staging)
#define WS_   132     // Wt row stride in floats (128 + 4 pad, 16B-multiple)
#define MROW_ 208     // spike-mask row stride in bytes per pixel (13*16)
#define TOFF_ 48      // spike-mask t stride in bytes (3*16)

// taus = jnp.linspace(1.5, 4.0, 8) in fp32, endpoint exact
__device__ __forceinline__ float tau_of(int e) {
    if (e == 7) return 4.0f;
    const float delta = 2.5f / 7.0f;
    return __fadd_rn(1.5f, __fmul_rn((float)e, delta));
}

// ---------------- Kernel 1: router LIF (tau=2) + exact spike mean over HW ----
__global__ __launch_bounds__(256) void k_router_lif(const float* __restrict__ x,
                                                    float* __restrict__ m) {
    int bc = blockIdx.x;
    int b = bc / C_, c = bc % C_;
    int p = threadIdx.x;
    int wv = threadIdx.x >> 6;
    __shared__ int cnt[T_][4];
    float v = 0.0f;
#pragma unroll
    for (int t = 0; t < T_; ++t) {
        float xv = x[((t * B_ + b) * C_ + c) * HW_ + p];
        v = __fadd_rn(v, __fdiv_rn(__fsub_rn(xv, v), 2.0f));
        bool s = (__fsub_rn(v, 1.0f) >= 0.0f);
        if (s) v = 0.0f;
        unsigned long long mask = __ballot(s);
        if ((threadIdx.x & 63) == 0) cnt[t][wv] = (int)__popcll(mask);
    }
    __syncthreads();
    if (threadIdx.x < T_) {
        int t = threadIdx.x;
        int tot = cnt[t][0] + cnt[t][1] + cnt[t][2] + cnt[t][3];
        m[(t * B_ + b) * C_ + c] = (float)tot * 0.00390625f;
    }
}

// ---------------- Kernel 2: logits -> softmax -> top2 -> compacted slots -----
__global__ __launch_bounds__(64) void k_router_route(const float* __restrict__ m,
        const float* __restrict__ rW, const float* __restrict__ rb,
        const float* __restrict__ rbs, const float* __restrict__ rbb,
        float* __restrict__ wslot, int* __restrict__ eslot) {
    int b = blockIdx.x;
    int tid = threadIdx.x;
    int combo = tid & 31, half = tid >> 5;
    int e = combo >> 2, t = combo & 3;
    float dot = 0.0f;
    int c0 = half * 192;
    for (int c = 0; c < 192; ++c)
        dot = fmaf(rW[e * C_ + c0 + c], m[(t * B_ + b) * C_ + c0 + c], dot);
    dot += __shfl_down(dot, 32);
    float denom = sqrtf(__fadd_rn(1.0f, 1e-5f));
    float Ar = __fdiv_rn(rbs[e], denom);
    float lt = __fadd_rn(__fmul_rn(__fadd_rn(dot, rb[e]), Ar), rbb[e]);
    lt = __fadd_rn(lt, __shfl_xor(lt, 1));
    lt = __fadd_rn(lt, __shfl_xor(lt, 2));
    __shared__ float lg[E_];
    if (half == 0 && t == 0) lg[e] = __fmul_rn(lt, 0.25f);
    __syncthreads();
    if (tid == 0) {
        float pr[E_];
        float mx = lg[0];
        for (int i = 1; i < E_; ++i) mx = fmaxf(mx, lg[i]);
        float s = 0.0f;
        for (int i = 0; i < E_; ++i) { pr[i] = expf(__fsub_rn(lg[i], mx)); s = __fadd_rn(s, pr[i]); }
        for (int i = 0; i < E_; ++i) pr[i] = __fdiv_rn(pr[i], s);
        int i0 = 0;
        for (int i = 1; i < E_; ++i) if (pr[i] > pr[i0]) i0 = i;
        int i1 = (i0 == 0) ? 1 : 0;
        for (int i = 0; i < E_; ++i) if (i != i0 && pr[i] > pr[i1]) i1 = i;
        float s2 = __fadd_rn(pr[i0], pr[i1]);
        wslot[b * 2 + 0] = __fdiv_rn(pr[i0], s2);
        wslot[b * 2 + 1] = __fdiv_rn(pr[i1], s2);
        eslot[b * 2 + 0] = i0;
        eslot[b * 2 + 1] = i1;
    }
}

// ---------------- fused expert: shared GEMM pass ----------------------------
// Wg: weight base for this (e, n-chunk): row o_local in [0,NC_), stride C_.
// smb: per-pixel spike-mask base (s?pb + px*MROW_). acc[t][j] accumulated over all 384 c.
__device__ __forceinline__ void conv_pass(const float* __restrict__ Wg,
                                          const unsigned char* __restrict__ smb,
                                          float* __restrict__ Wt,
                                          float (&acc)[T_][8],
                                          int tid, int g) {
#pragma unroll 1
    for (int kt = 0; kt < C_ / KT_; ++kt) {
        __syncthreads();
        // stage 128x128 weight tile, [o][c], coalesced float4 global -> b128 LDS
        for (int i = tid; i < NC_ * KT_ / 4; i += TH_) {
            int o_ = i >> 5;
            int c4 = (i & 31) << 2;
            const float4 wv = *reinterpret_cast<const float4*>(
                &Wg[(size_t)o_ * C_ + kt * KT_ + c4]);
            *reinterpret_cast<float4*>(&Wt[o_ * WS_ + c4]) = wv;
        }
        __syncthreads();
        // this thread's spike bits for 128 channels x 4 t (registers for whole kt)
        uint4 m0 = *reinterpret_cast<const uint4*>(smb + 0 * TOFF_ + kt * 16);
        uint4 m1 = *reinterpret_cast<const uint4*>(smb + 1 * TOFF_ + kt * 16);
        uint4 m2 = *reinterpret_cast<const uint4*>(smb + 2 * TOFF_ + kt * 16);
        uint4 m3 = *reinterpret_cast<const uint4*>(smb + 3 * TOFF_ + kt * 16);
        const float* wp = Wt + g * 8 * WS_;
#pragma unroll
        for (int w_ = 0; w_ < 4; ++w_) {
            unsigned b0 = (&m0.x)[w_];
            unsigned b1 = (&m1.x)[w_];
            unsigned b2 = (&m2.x)[w_];
            unsigned b3 = (&m3.x)[w_];
#pragma unroll 2
            for (int s = 0; s < 8; ++s) {
                int c0 = w_ * 32 + s * 4;
                unsigned u0 = b0 >> (s * 4);
                unsigned u1 = b1 >> (s * 4);
                unsigned u2 = b2 >> (s * 4);
                unsigned u3 = b3 >> (s * 4);
                float sv0q0 = (float)(u0 & 1u), sv0q1 = (float)((u0 >> 1) & 1u);
                float sv0q2 = (float)((u0 >> 2) & 1u), sv0q3 = (float)((u0 >> 3) & 1u);
                float sv1q0 = (float)(u1 & 1u), sv1q1 = (float)((u1 >> 1) & 1u);
                float sv1q2 = (float)((u1 >> 2) & 1u), sv1q3 = (float)((u1 >> 3) & 1u);
                float sv2q0 = (float)(u2 & 1u), sv2q1 = (float)((u2 >> 1) & 1u);
                float sv2q2 = (float)((u2 >> 2) & 1u), sv2q3 = (float)((u2 >> 3) & 1u);
                float sv3q0 = (float)(u3 & 1u), sv3q1 = (float)((u3 >> 1) & 1u);
                float sv3q2 = (float)((u3 >> 2) & 1u), sv3q3 = (float)((u3 >> 3) & 1u);
#pragma unroll
                for (int j = 0; j < 8; ++j) {
                    const float4 w4 = *reinterpret_cast<const float4*>(&wp[j * WS_ + c0]);
                    acc[0][j] = fmaf(sv0q0, w4.x, acc[0][j]);
                    acc[0][j] = fmaf(sv0q1, w4.y, acc[0][j]);
                    acc[0][j] = fmaf(sv0q2, w4.z, acc[0][j]);
                    acc[0][j] = fmaf(sv0q3, w4.w, acc[0][j]);
                    acc[1][j] = fmaf(sv1q0, w4.x, acc[1][j]);
                    acc[1][j] = fmaf(sv1q1, w4.y, acc[1][j]);
                    acc[1][j] = fmaf(sv1q2, w4.z, acc[1][j]);
                    acc[1][j] = fmaf(sv1q3, w4.w, acc[1][j]);
                    acc[2][j] = fmaf(sv2q0, w4.x, acc[2][j]);
                    acc[2][j] = fmaf(sv2q1, w4.y, acc[2][j]);
                    acc[2][j] = fmaf(sv2q2, w4.z, acc[2][j]);
                    acc[2][j] = fmaf(sv2q3, w4.w, acc[2][j]);
                    acc[3][j] = fmaf(sv3q0, w4.x, acc[3][j]);
                    acc[3][j] = fmaf(sv3q1, w4.y, acc[3][j]);
                    acc[3][j] = fmaf(sv3q2, w4.z, acc[3][j]);
                    acc[3][j] = fmaf(sv3q3, w4.w, acc[3][j]);
                }
            }
        }
    }
}

// grid: 32 slots x 8 pixel-tiles = 256 blocks, 512 threads (32 px x 16 groups)
__global__ __launch_bounds__(TH_, 2) void k_expert(
        const float* __restrict__ x,
        const float* __restrict__ W1, const float* __restrict__ b1,
        const float* __restrict__ s1sc, const float* __restrict__ s1bi,
        const float* __restrict__ W2, const float* __restrict__ b2,
        const float* __restrict__ s2sc, const float* __restrict__ s2bi,
        const float* __restrict__ wslot, const int* __restrict__ eslot,
        float* __restrict__ out) {
    int blk = blockIdx.x;
    int ptile = blk & 7;
    int slot = blk >> 3;
    int b = slot >> 1;
    int rank = slot & 1;
    int e = eslot[b * 2 + rank];
    float wgt = wslot[b * 2 + rank];

    __shared__ float A1s[C_], B1s[C_], BB1s[C_], A2s[C_], B2s[C_], BB2s[C_];
    __shared__ __align__(16) unsigned char s1pb[P_ * MROW_];   // [px][t][c-bits]
    __shared__ __align__(16) unsigned char s2pb[P_ * MROW_];
    __shared__ __align__(16) float Wt[NC_ * WS_];

    int tid = threadIdx.x;
    int px = tid & 31;
    int g  = tid >> 5;               // 0..15, uniform per half-wave
    int p  = ptile * P_ + px;

    float denom = sqrtf(__fadd_rn(1.0f, 1e-5f));
    if (tid < C_) {
        int o = tid;
        A1s[o]  = __fdiv_rn(s1sc[e * C_ + o], denom);
        B1s[o]  = b1[e * C_ + o];
        BB1s[o] = s1bi[e * C_ + o];
        A2s[o]  = __fdiv_rn(s2sc[e * C_ + o], denom);
        B2s[o]  = b2[e * C_ + o];
        BB2s[o] = s2bi[e * C_ + o];
    }

    float tau = tau_of(e);

    // ---- phase 1: LIF1 -> bit-plane masks s1pb[px][t][c-word] ----
    // thread (px, cb) handles 32 channels sequentially; coalesced per half-wave.
    if (g < 12) {
        int cb = g;
        unsigned wd0 = 0, wd1 = 0, wd2 = 0, wd3 = 0;
#pragma unroll 4
        for (int lc = 0; lc < 32; ++lc) {
            int c = cb * 32 + lc;
            float v = 0.0f;
            float xv;
            xv = x[((0 * B_ + b) * C_ + c) * HW_ + p];
            v = __fadd_rn(v, __fdiv_rn(__fsub_rn(xv, v), tau));
            if (__fsub_rn(v, 1.0f) >= 0.0f) { wd0 |= (1u << lc); v = 0.0f; }
            xv = x[((1 * B_ + b) * C_ + c) * HW_ + p];
            v = __fadd_rn(v, __fdiv_rn(__fsub_rn(xv, v), tau));
            if (__fsub_rn(v, 1.0f) >= 0.0f) { wd1 |= (1u << lc); v = 0.0f; }
            xv = x[((2 * B_ + b) * C_ + c) * HW_ + p];
            v = __fadd_rn(v, __fdiv_rn(__fsub_rn(xv, v), tau));
            if (__fsub_rn(v, 1.0f) >= 0.0f) { wd2 |= (1u << lc); v = 0.0f; }
            xv = x[((3 * B_ + b) * C_ + c) * HW_ + p];
            v = __fadd_rn(v, __fdiv_rn(__fsub_rn(xv, v), tau));
            if (__fsub_rn(v, 1.0f) >= 0.0f) { wd3 |= (1u << lc); v = 0.0f; }
        }
        *reinterpret_cast<unsigned*>(&s1pb[px * MROW_ + 0 * TOFF_ + cb * 4]) = wd0;
        *reinterpret_cast<unsigned*>(&s1pb[px * MROW_ + 1 * TOFF_ + cb * 4]) = wd1;
        *reinterpret_cast<unsigned*>(&s1pb[px * MROW_ + 2 * TOFF_ + cb * 4]) = wd2;
        *reinterpret_cast<unsigned*>(&s1pb[px * MROW_ + 3 * TOFF_ + cb * 4]) = wd3;
    }

    const float* W1e = W1 + (size_t)e * C_ * C_;
    const float* W2e = W2 + (size_t)e * C_ * C_;
    const unsigned char* smb1 = s1pb + px * MROW_;
    unsigned char* smb2w = s2pb + px * MROW_;

    // ---- pass A: conv1 + BN + residual -> identity out + LIF2 -> s2 masks ----
#pragma unroll 1
    for (int n = 0; n < C_ / NC_; ++n) {
        float acc[T_][8];
#pragma unroll
        for (int t = 0; t < T_; ++t)
#pragma unroll
            for (int j = 0; j < 8; ++j) acc[t][j] = 0.0f;

        conv_pass(W1e + (size_t)(n * NC_) * C_, smb1, Wt, acc, tid, g);

        unsigned sb[T_] = {0, 0, 0, 0};
#pragma unroll
        for (int j = 0; j < 8; ++j) {
            int o = n * NC_ + g * 8 + j;
            float a1 = A1s[o], bv = B1s[o], bbv = BB1s[o];
            float v2s = 0.0f;
#pragma unroll
            for (int t = 0; t < T_; ++t) {
                int gi = ((t * B_ + b) * C_ + o) * HW_ + p;
                float xv = x[gi];
                float h = __fadd_rn(xv, __fadd_rn(__fmul_rn(__fadd_rn(acc[t][j], bv), a1), bbv));
                atomicAdd(&out[gi], wgt * h);
                v2s = __fadd_rn(v2s, __fdiv_rn(__fsub_rn(h, v2s), tau));
                if (__fsub_rn(v2s, 1.0f) >= 0.0f) { sb[t] |= (1u << j); v2s = 0.0f; }
            }
        }
        smb2w[0 * TOFF_ + n * 16 + g] = (unsigned char)sb[0];
        smb2w[1 * TOFF_ + n * 16 + g] = (unsigned char)sb[1];
        smb2w[2 * TOFF_ + n * 16 + g] = (unsigned char)sb[2];
        smb2w[3 * TOFF_ + n * 16 + g] = (unsigned char)sb[3];
    }

    // ---- pass B: conv2 + BN + weighted atomic out ----
#pragma unroll 1
    for (int n = 0; n < C_ / NC_; ++n) {
        float acc[T_][8];
#pragma unroll
        for (int t = 0; t < T_; ++t)
#pragma unroll
            for (int j = 0; j < 8; ++j) acc[t][j] = 0.0f;

        conv_pass(W2e + (size_t)(n * NC_) * C_, smb2w, Wt, acc, tid, g);

#pragma unroll
        for (int j = 0; j < 8; ++j) {
            int o = n * NC_ + g * 8 + j;
            float a2 = A2s[o], bv = B2s[o], bbv = BB2s[o];
#pragma unroll
            for (int t = 0; t < T_; ++t) {
                int gi = ((t * B_ + b) * C_ + o) * HW_ + p;
                float val = wgt * __fadd_rn(__fmul_rn(__fadd_rn(acc[t][j], bv), a2), bbv);
                atomicAdd(&out[gi], val);
            }
        }
    }
}

extern "C" void kernel_launch(void* const* d_in, const int* in_sizes, int n_in,
                              void* d_out, int out_size, void* d_ws, size_t ws_size,
                              hipStream_t stream) {
    const float* x    = (const float*)d_in[0];
    const float* rW   = (const float*)d_in[1];
    const float* rb   = (const float*)d_in[2];
    const float* rbs  = (const float*)d_in[3];
    const float* rbb  = (const float*)d_in[4];
    const float* W1   = (const float*)d_in[5];
    const float* b1   = (const float*)d_in[6];
    const float* s1sc = (const float*)d_in[7];
    const float* s1bi = (const float*)d_in[8];
    const float* W2   = (const float*)d_in[9];
    const float* b2   = (const float*)d_in[10];
    const float* s2sc = (const float*)d_in[11];
    const float* s2bi = (const float*)d_in[12];
    float* out = (float*)d_out;

    float* wsf   = (float*)d_ws;
    float* wslot = wsf;                    // 32 floats
    int*   eslot = (int*)(wsf + 32);       // 32 ints
    float* m     = wsf + 64;               // T_*B_*C_ floats

    hipMemsetAsync(d_out, 0, (size_t)out_size * sizeof(float), stream);
    hipLaunchKernelGGL(k_router_lif, dim3(B_ * C_), dim3(256), 0, stream, x, m);
    hipLaunchKernelGGL(k_router_route, dim3(B_), dim3(64), 0, stream,
                       m, rW, rb, rbs, rbb, wslot, eslot);
    hipLaunchKernelGGL(k_expert, dim3(32 * PT_), dim3(TH_), 0, stream,
                       x, W1, b1, s1sc, s1bi, W2, b2, s2sc, s2bi, wslot, eslot, out);
}

// Round 3
// 235.254 us; speedup vs baseline: 2.5841x; 1.9827x over previous
//
#include <hip/hip_runtime.h>
#include <math.h>

#define T_  4
#define B_  16
#define C_  384
#define HW_ 256
#define E_  8

typedef __attribute__((ext_vector_type(8))) __bf16 bf16x8;
typedef __attribute__((ext_vector_type(4))) float f32x4;

union FragU { uint4 u; bf16x8 v; };

// taus = jnp.linspace(1.5, 4.0, 8) in fp32, endpoint exact
__device__ __forceinline__ float tau_of(int e) {
    if (e == 7) return 4.0f;
    const float delta = 2.5f / 7.0f;
    return __fadd_rn(1.5f, __fmul_rn((float)e, delta));
}

// ---------------- Kernel 1: router LIF (tau=2) + exact spike mean over HW ----
__global__ __launch_bounds__(256) void k_router_lif(const float* __restrict__ x,
                                                    float* __restrict__ m) {
    int bc = blockIdx.x;
    int b = bc / C_, c = bc % C_;
    int p = threadIdx.x;
    int wv = threadIdx.x >> 6;
    __shared__ int cnt[T_][4];
    float v = 0.0f;
#pragma unroll
    for (int t = 0; t < T_; ++t) {
        float xv = x[((t * B_ + b) * C_ + c) * HW_ + p];
        v = __fadd_rn(v, __fdiv_rn(__fsub_rn(xv, v), 2.0f));
        bool s = (__fsub_rn(v, 1.0f) >= 0.0f);
        if (s) v = 0.0f;
        unsigned long long mask = __ballot(s);
        if ((threadIdx.x & 63) == 0) cnt[t][wv] = (int)__popcll(mask);
    }
    __syncthreads();
    if (threadIdx.x < T_) {
        int t = threadIdx.x;
        int tot = cnt[t][0] + cnt[t][1] + cnt[t][2] + cnt[t][3];
        m[(t * B_ + b) * C_ + c] = (float)tot * 0.00390625f;
    }
}

// ---------------- Kernel 2: logits -> softmax -> top2 -> compacted slots -----
__global__ __launch_bounds__(64) void k_router_route(const float* __restrict__ m,
        const float* __restrict__ rW, const float* __restrict__ rb,
        const float* __restrict__ rbs, const float* __restrict__ rbb,
        float* __restrict__ wslot, int* __restrict__ eslot) {
    int b = blockIdx.x;
    int tid = threadIdx.x;
    int combo = tid & 31, half = tid >> 5;
    int e = combo >> 2, t = combo & 3;
    float dot = 0.0f;
    int c0 = half * 192;
    for (int c = 0; c < 192; ++c)
        dot = fmaf(rW[e * C_ + c0 + c], m[(t * B_ + b) * C_ + c0 + c], dot);
    dot += __shfl_down(dot, 32);
    float denom = sqrtf(__fadd_rn(1.0f, 1e-5f));
    float Ar = __fdiv_rn(rbs[e], denom);
    float lt = __fadd_rn(__fmul_rn(__fadd_rn(dot, rb[e]), Ar), rbb[e]);
    lt = __fadd_rn(lt, __shfl_xor(lt, 1));
    lt = __fadd_rn(lt, __shfl_xor(lt, 2));
    __shared__ float lg[E_];
    if (half == 0 && t == 0) lg[e] = __fmul_rn(lt, 0.25f);
    __syncthreads();
    if (tid == 0) {
        float pr[E_];
        float mx = lg[0];
        for (int i = 1; i < E_; ++i) mx = fmaxf(mx, lg[i]);
        float s = 0.0f;
        for (int i = 0; i < E_; ++i) { pr[i] = expf(__fsub_rn(lg[i], mx)); s = __fadd_rn(s, pr[i]); }
        for (int i = 0; i < E_; ++i) pr[i] = __fdiv_rn(pr[i], s);
        int i0 = 0;
        for (int i = 1; i < E_; ++i) if (pr[i] > pr[i0]) i0 = i;
        int i1 = (i0 == 0) ? 1 : 0;
        for (int i = 0; i < E_; ++i) if (i != i0 && pr[i] > pr[i1]) i1 = i;
        float s2 = __fadd_rn(pr[i0], pr[i1]);
        wslot[b * 2 + 0] = __fdiv_rn(pr[i0], s2);
        wslot[b * 2 + 1] = __fdiv_rn(pr[i1], s2);
        eslot[b * 2 + 0] = i0;
        eslot[b * 2 + 1] = i1;
    }
}

// ---------------- Kernel 3: split W (fp32) -> Whi/Wlo bf16, fragment layout --
// frag id f = ((e*2+cv)*12 + ksub)*24 + osub ; within frag: [lane][j] (512 ushorts)
// element (lane l, j): o = osub*16 + (l&15), c = ksub*32 + (l>>4)*8 + j
__global__ __launch_bounds__(256) void k_wsplit(const float* __restrict__ W1,
        const float* __restrict__ W2,
        unsigned short* __restrict__ Whif, unsigned short* __restrict__ Wlof) {
    int tid = blockIdx.x * 256 + threadIdx.x;    // 294912 total
    int l = tid & 63;
    int f = tid >> 6;                            // 0..4607
    int osub = f % 24;
    int ksub = (f / 24) % 12;
    int cv = (f / 288) & 1;
    int e = f / 576;
    const float* Wsrc = (cv == 0 ? W1 : W2) + (size_t)e * C_ * C_;
    int o = osub * 16 + (l & 15);
    int c0 = ksub * 32 + (l >> 4) * 8;
    const float* src = Wsrc + (size_t)o * C_ + c0;
    unsigned hw[8], lw[8];
#pragma unroll
    for (int j = 0; j < 8; ++j) {
        float w = src[j];
        unsigned u = __float_as_uint(w);
        unsigned hi = (u + 0x7FFFu + ((u >> 16) & 1u)) >> 16;
        float hf = __uint_as_float(hi << 16);
        float res = __fsub_rn(w, hf);
        unsigned ru = __float_as_uint(res);
        unsigned lo = (ru + 0x7FFFu + ((ru >> 16) & 1u)) >> 16;
        hw[j] = hi & 0xFFFFu;
        lw[j] = lo & 0xFFFFu;
    }
    size_t dst = (size_t)f * 512 + (size_t)l * 8;
    uint4 hv = make_uint4(hw[0] | (hw[1] << 16), hw[2] | (hw[3] << 16),
                          hw[4] | (hw[5] << 16), hw[6] | (hw[7] << 16));
    uint4 lv = make_uint4(lw[0] | (lw[1] << 16), lw[2] | (lw[3] << 16),
                          lw[4] | (lw[5] << 16), lw[6] | (lw[7] << 16));
    *reinterpret_cast<uint4*>(Whif + dst) = hv;
    *reinterpret_cast<uint4*>(Wlof + dst) = lv;
}

// ---------------- Kernel 4: fused MFMA expert -------------------------------
// grid: 32 slots x 16 pixel-tiles (16 px) = 512 blocks, 512 threads (8 waves).
// Wave w owns output channels [w*48, w*48+48), all 4 t, 16 px.
// A = W (m=o, k=c) from precomputed frags; B = spikes (k=c, n=px) from LDS bits.
// D layout (m89): col = lane&15 = px, row = (lane>>4)*4 + reg = o_local16.
__global__ __launch_bounds__(512, 2) void k_expert(
        const float* __restrict__ x,
        const unsigned short* __restrict__ Whif, const unsigned short* __restrict__ Wlof,
        const float* __restrict__ b1, const float* __restrict__ s1sc, const float* __restrict__ s1bi,
        const float* __restrict__ b2, const float* __restrict__ s2sc, const float* __restrict__ s2bi,
        const float* __restrict__ wslot, const int* __restrict__ eslot,
        float* __restrict__ out) {
    int blk = blockIdx.x;
    int ptile = blk & 15;
    int slot = blk >> 4;             // 0..31
    int b = slot >> 1;
    int rank = slot & 1;
    int e = eslot[b * 2 + rank];
    float wgt = wslot[b * 2 + rank];
    float tau = tau_of(e);

    __shared__ unsigned char s1m[T_ * 16 * 96];   // [t][pl][cg] nibble-bytes (4 c's per byte)
    __shared__ unsigned char s2m[T_ * 16 * 96];
    __shared__ uint2 LUT[16];                     // nibble -> 2 words (4 bf16 0/1)
    __shared__ float A1s[C_], B1s[C_], BB1s[C_], A2s[C_], B2s[C_], BB2s[C_];

    int tid = threadIdx.x;
    int wave = tid >> 6;
    int lane = tid & 63;
    int q = lane >> 4;               // quad
    int pl = lane & 15;
    int p = ptile * 16 + pl;

    if (tid < 16) {
        unsigned n = tid;
        LUT[n].x = ((n & 1u) ? 0x3F80u : 0u) | ((n & 2u) ? 0x3F800000u : 0u);
        LUT[n].y = ((n & 4u) ? 0x3F80u : 0u) | ((n & 8u) ? 0x3F800000u : 0u);
    }
    float denom = sqrtf(__fadd_rn(1.0f, 1e-5f));
    if (tid < C_) {
        int o = tid;
        A1s[o]  = __fdiv_rn(s1sc[e * C_ + o], denom);
        B1s[o]  = b1[e * C_ + o];
        BB1s[o] = s1bi[e * C_ + o];
        A2s[o]  = __fdiv_rn(s2sc[e * C_ + o], denom);
        B2s[o]  = b2[e * C_ + o];
        BB2s[o] = s2bi[e * C_ + o];
    }

    // ---- LIF1: 4-channel chains -> nibble bitplanes in s1m ----
#pragma unroll 1
    for (int task = tid; task < 96 * 16; task += 512) {
        int cg = task >> 4;
        int tpl = task & 15;
        int tp = ptile * 16 + tpl;
        int c = cg * 4;
        float v0 = 0.f, v1 = 0.f, v2 = 0.f, v3 = 0.f;
#pragma unroll
        for (int t = 0; t < T_; ++t) {
            int base = ((t * B_ + b) * C_ + c) * HW_ + tp;
            float x0 = x[base], x1 = x[base + HW_], x2 = x[base + 2 * HW_], x3 = x[base + 3 * HW_];
            unsigned nb = 0;
            v0 = __fadd_rn(v0, __fdiv_rn(__fsub_rn(x0, v0), tau));
            if (__fsub_rn(v0, 1.0f) >= 0.0f) { nb |= 1u; v0 = 0.f; }
            v1 = __fadd_rn(v1, __fdiv_rn(__fsub_rn(x1, v1), tau));
            if (__fsub_rn(v1, 1.0f) >= 0.0f) { nb |= 2u; v1 = 0.f; }
            v2 = __fadd_rn(v2, __fdiv_rn(__fsub_rn(x2, v2), tau));
            if (__fsub_rn(v2, 1.0f) >= 0.0f) { nb |= 4u; v2 = 0.f; }
            v3 = __fadd_rn(v3, __fdiv_rn(__fsub_rn(x3, v3), tau));
            if (__fsub_rn(v3, 1.0f) >= 0.0f) { nb |= 8u; v3 = 0.f; }
            s1m[(t * 16 + tpl) * 96 + cg] = (unsigned char)nb;
        }
    }
    __syncthreads();

    // A-frag base offsets (ushort index): frag f = ((e*2+cv)*12 + ksub)*24 + (wave*3+osub)
    const unsigned base_e = (unsigned)(e * 2) * 12u * 24u * 512u;
    const unsigned lane8 = (unsigned)lane * 8u;

    // =================== conv1 ===================
    {
        f32x4 acc[3][4];
#pragma unroll
        for (int os = 0; os < 3; ++os)
#pragma unroll
            for (int t = 0; t < T_; ++t) acc[os][t] = (f32x4)0.0f;

        const unsigned char* sb = s1m;
#pragma unroll 1
        for (int ksub = 0; ksub < 12; ++ksub) {
            // B frags for 4 t
            FragU bf[T_];
#pragma unroll
            for (int t = 0; t < T_; ++t) {
                unsigned sv = *reinterpret_cast<const unsigned short*>(
                    sb + (t * 16 + pl) * 96 + ksub * 8 + q * 2);
                uint2 L0 = LUT[sv & 15u];
                uint2 L1 = LUT[(sv >> 8) & 15u];
                bf[t].u = make_uint4(L0.x, L0.y, L1.x, L1.y);
            }
            // A frags (3 osub, hi+lo)
            unsigned fo = base_e + (unsigned)ksub * 24u * 512u + (unsigned)(wave * 3) * 512u + lane8;
            FragU ah0, al0, ah1, al1, ah2, al2;
            ah0.u = *reinterpret_cast<const uint4*>(Whif + fo);
            al0.u = *reinterpret_cast<const uint4*>(Wlof + fo);
            ah1.u = *reinterpret_cast<const uint4*>(Whif + fo + 512u);
            al1.u = *reinterpret_cast<const uint4*>(Wlof + fo + 512u);
            ah2.u = *reinterpret_cast<const uint4*>(Whif + fo + 1024u);
            al2.u = *reinterpret_cast<const uint4*>(Wlof + fo + 1024u);
#pragma unroll
            for (int t = 0; t < T_; ++t) {
                acc[0][t] = __builtin_amdgcn_mfma_f32_16x16x32_bf16(al0.v, bf[t].v, acc[0][t], 0, 0, 0);
                acc[0][t] = __builtin_amdgcn_mfma_f32_16x16x32_bf16(ah0.v, bf[t].v, acc[0][t], 0, 0, 0);
                acc[1][t] = __builtin_amdgcn_mfma_f32_16x16x32_bf16(al1.v, bf[t].v, acc[1][t], 0, 0, 0);
                acc[1][t] = __builtin_amdgcn_mfma_f32_16x16x32_bf16(ah1.v, bf[t].v, acc[1][t], 0, 0, 0);
                acc[2][t] = __builtin_amdgcn_mfma_f32_16x16x32_bf16(al2.v, bf[t].v, acc[2][t], 0, 0, 0);
                acc[2][t] = __builtin_amdgcn_mfma_f32_16x16x32_bf16(ah2.v, bf[t].v, acc[2][t], 0, 0, 0);
            }
        }

        // epilogue: h = x + bn1(y), out += wgt*h, LIF2 -> s2m nibbles
#pragma unroll
        for (int os = 0; os < 3; ++os) {
            float v2s[4] = {0.f, 0.f, 0.f, 0.f};
#pragma unroll
            for (int t = 0; t < T_; ++t) {
                unsigned nb = 0;
#pragma unroll
                for (int r = 0; r < 4; ++r) {
                    int o = wave * 48 + os * 16 + q * 4 + r;
                    int gi = ((t * B_ + b) * C_ + o) * HW_ + p;
                    float y = acc[os][t][r];
                    float h = __fadd_rn(x[gi],
                        __fadd_rn(__fmul_rn(__fadd_rn(y, B1s[o]), A1s[o]), BB1s[o]));
                    atomicAdd(&out[gi], wgt * h);
                    v2s[r] = __fadd_rn(v2s[r], __fdiv_rn(__fsub_rn(h, v2s[r]), tau));
                    if (__fsub_rn(v2s[r], 1.0f) >= 0.0f) { nb |= (1u << r); v2s[r] = 0.f; }
                }
                s2m[(t * 16 + pl) * 96 + wave * 12 + os * 4 + q] = (unsigned char)nb;
            }
        }
    }
    __syncthreads();

    // =================== conv2 ===================
    {
        f32x4 acc[3][4];
#pragma unroll
        for (int os = 0; os < 3; ++os)
#pragma unroll
            for (int t = 0; t < T_; ++t) acc[os][t] = (f32x4)0.0f;

        const unsigned base_e2 = base_e + 12u * 24u * 512u;   // cv=1
        const unsigned char* sb = s2m;
#pragma unroll 1
        for (int ksub = 0; ksub < 12; ++ksub) {
            FragU bf[T_];
#pragma unroll
            for (int t = 0; t < T_; ++t) {
                unsigned sv = *reinterpret_cast<const unsigned short*>(
                    sb + (t * 16 + pl) * 96 + ksub * 8 + q * 2);
                uint2 L0 = LUT[sv & 15u];
                uint2 L1 = LUT[(sv >> 8) & 15u];
                bf[t].u = make_uint4(L0.x, L0.y, L1.x, L1.y);
            }
            unsigned fo = base_e2 + (unsigned)ksub * 24u * 512u + (unsigned)(wave * 3) * 512u + lane8;
            FragU ah0, al0, ah1, al1, ah2, al2;
            ah0.u = *reinterpret_cast<const uint4*>(Whif + fo);
            al0.u = *reinterpret_cast<const uint4*>(Wlof + fo);
            ah1.u = *reinterpret_cast<const uint4*>(Whif + fo + 512u);
            al1.u = *reinterpret_cast<const uint4*>(Wlof + fo + 512u);
            ah2.u = *reinterpret_cast<const uint4*>(Whif + fo + 1024u);
            al2.u = *reinterpret_cast<const uint4*>(Wlof + fo + 1024u);
#pragma unroll
            for (int t = 0; t < T_; ++t) {
                acc[0][t] = __builtin_amdgcn_mfma_f32_16x16x32_bf16(al0.v, bf[t].v, acc[0][t], 0, 0, 0);
                acc[0][t] = __builtin_amdgcn_mfma_f32_16x16x32_bf16(ah0.v, bf[t].v, acc[0][t], 0, 0, 0);
                acc[1][t] = __builtin_amdgcn_mfma_f32_16x16x32_bf16(al1.v, bf[t].v, acc[1][t], 0, 0, 0);
                acc[1][t] = __builtin_amdgcn_mfma_f32_16x16x32_bf16(ah1.v, bf[t].v, acc[1][t], 0, 0, 0);
                acc[2][t] = __builtin_amdgcn_mfma_f32_16x16x32_bf16(al2.v, bf[t].v, acc[2][t], 0, 0, 0);
                acc[2][t] = __builtin_amdgcn_mfma_f32_16x16x32_bf16(ah2.v, bf[t].v, acc[2][t], 0, 0, 0);
            }
        }

#pragma unroll
        for (int os = 0; os < 3; ++os) {
#pragma unroll
            for (int t = 0; t < T_; ++t) {
#pragma unroll
                for (int r = 0; r < 4; ++r) {
                    int o = wave * 48 + os * 16 + q * 4 + r;
                    int gi = ((t * B_ + b) * C_ + o) * HW_ + p;
                    float y = acc[os][t][r];
                    float val = wgt * __fadd_rn(__fmul_rn(__fadd_rn(y, B2s[o]), A2s[o]), BB2s[o]);
                    atomicAdd(&out[gi], val);
                }
            }
        }
    }
}

extern "C" void kernel_launch(void* const* d_in, const int* in_sizes, int n_in,
                              void* d_out, int out_size, void* d_ws, size_t ws_size,
                              hipStream_t stream) {
    const float* x    = (const float*)d_in[0];
    const float* rW   = (const float*)d_in[1];
    const float* rb   = (const float*)d_in[2];
    const float* rbs  = (const float*)d_in[3];
    const float* rbb  = (const float*)d_in[4];
    const float* W1   = (const float*)d_in[5];
    const float* b1   = (const float*)d_in[6];
    const float* s1sc = (const float*)d_in[7];
    const float* s1bi = (const float*)d_in[8];
    const float* W2   = (const float*)d_in[9];
    const float* b2   = (const float*)d_in[10];
    const float* s2sc = (const float*)d_in[11];
    const float* s2bi = (const float*)d_in[12];
    float* out = (float*)d_out;

    // ws layout: Whif (4718592 B) | Wlof (4718592 B) | wslot(32f) | eslot(32i) | m(24576f)
    unsigned short* Whif = (unsigned short*)d_ws;
    unsigned short* Wlof = Whif + 2359296;
    float* tail  = (float*)((char*)d_ws + 9437184);
    float* wslot = tail;
    int*   eslot = (int*)(tail + 32);
    float* m     = tail + 64;

    hipMemsetAsync(d_out, 0, (size_t)out_size * sizeof(float), stream);
    hipLaunchKernelGGL(k_wsplit, dim3(1152), dim3(256), 0, stream, W1, W2, Whif, Wlof);
    hipLaunchKernelGGL(k_router_lif, dim3(B_ * C_), dim3(256), 0, stream, x, m);
    hipLaunchKernelGGL(k_router_route, dim3(B_), dim3(64), 0, stream,
                       m, rW, rb, rbs, rbb, wslot, eslot);
    hipLaunchKernelGGL(k_expert, dim3(32 * 16), dim3(512), 0, stream,
                       x, Whif, Wlof, b1, s1sc, s1bi, b2, s2sc, s2bi, wslot, eslot, out);
}

// Round 4
// 215.900 us; speedup vs baseline: 2.8158x; 1.0896x over previous
//
#include <hip/hip_runtime.h>
#include <math.h>

#define T_  4
#define B_  16
#define C_  384
#define HW_ 256
#define E_  8

typedef __attribute__((ext_vector_type(8))) __bf16 bf16x8;
typedef __attribute__((ext_vector_type(4))) float f32x4;

union FragU { uint4 u; bf16x8 v; };

// taus = jnp.linspace(1.5, 4.0, 8) in fp32, endpoint exact
__device__ __forceinline__ float tau_of(int e) {
    if (e == 7) return 4.0f;
    const float delta = 2.5f / 7.0f;
    return __fadd_rn(1.5f, __fmul_rn((float)e, delta));
}

// bits of m (8 spikes) -> bf16x8 {0,1} fragment
__device__ __forceinline__ FragU expand_mask(unsigned m) {
    FragU f;
    f.u.x = ((m & 1u)   ? 0x3F80u : 0u) | ((m & 2u)   ? 0x3F800000u : 0u);
    f.u.y = ((m & 4u)   ? 0x3F80u : 0u) | ((m & 8u)   ? 0x3F800000u : 0u);
    f.u.z = ((m & 16u)  ? 0x3F80u : 0u) | ((m & 32u)  ? 0x3F800000u : 0u);
    f.u.w = ((m & 64u)  ? 0x3F80u : 0u) | ((m & 128u) ? 0x3F800000u : 0u);
    return f;
}

// ---------------- Kernel 1: router LIF (tau=2) + exact spike mean + out-zero -
__global__ __launch_bounds__(256) void k_router_lif(const float* __restrict__ x,
                                                    float* __restrict__ m,
                                                    float4* __restrict__ outz) {
    int bc = blockIdx.x;
    int b = bc / C_, c = bc % C_;
    int p = threadIdx.x;
    int wv = threadIdx.x >> 6;
    // zero 4 floats of out per thread (6144*256*4 == T*B*C*HW exactly)
    outz[bc * 256 + threadIdx.x] = make_float4(0.f, 0.f, 0.f, 0.f);
    __shared__ int cnt[T_][4];
    float v = 0.0f;
#pragma unroll
    for (int t = 0; t < T_; ++t) {
        float xv = x[((t * B_ + b) * C_ + c) * HW_ + p];
        v = __fadd_rn(v, __fdiv_rn(__fsub_rn(xv, v), 2.0f));
        bool s = (__fsub_rn(v, 1.0f) >= 0.0f);
        if (s) v = 0.0f;
        unsigned long long mask = __ballot(s);
        if ((threadIdx.x & 63) == 0) cnt[t][wv] = (int)__popcll(mask);
    }
    __syncthreads();
    if (threadIdx.x < T_) {
        int t = threadIdx.x;
        int tot = cnt[t][0] + cnt[t][1] + cnt[t][2] + cnt[t][3];
        m[(t * B_ + b) * C_ + c] = (float)tot * 0.00390625f;
    }
}

// ---------------- Kernel 2: logits -> softmax -> top2 -> compacted slots -----
__global__ __launch_bounds__(64) void k_router_route(const float* __restrict__ m,
        const float* __restrict__ rW, const float* __restrict__ rb,
        const float* __restrict__ rbs, const float* __restrict__ rbb,
        float* __restrict__ wslot, int* __restrict__ eslot) {
    int b = blockIdx.x;
    int tid = threadIdx.x;
    int combo = tid & 31, half = tid >> 5;
    int e = combo >> 2, t = combo & 3;
    float dot = 0.0f;
    int c0 = half * 192;
    for (int c = 0; c < 192; ++c)
        dot = fmaf(rW[e * C_ + c0 + c], m[(t * B_ + b) * C_ + c0 + c], dot);
    dot += __shfl_down(dot, 32);
    float denom = sqrtf(__fadd_rn(1.0f, 1e-5f));
    float Ar = __fdiv_rn(rbs[e], denom);
    float lt = __fadd_rn(__fmul_rn(__fadd_rn(dot, rb[e]), Ar), rbb[e]);
    lt = __fadd_rn(lt, __shfl_xor(lt, 1));
    lt = __fadd_rn(lt, __shfl_xor(lt, 2));
    __shared__ float lg[E_];
    if (half == 0 && t == 0) lg[e] = __fmul_rn(lt, 0.25f);
    __syncthreads();
    if (tid == 0) {
        float pr[E_];
        float mx = lg[0];
        for (int i = 1; i < E_; ++i) mx = fmaxf(mx, lg[i]);
        float s = 0.0f;
        for (int i = 0; i < E_; ++i) { pr[i] = expf(__fsub_rn(lg[i], mx)); s = __fadd_rn(s, pr[i]); }
        for (int i = 0; i < E_; ++i) pr[i] = __fdiv_rn(pr[i], s);
        int i0 = 0;
        for (int i = 1; i < E_; ++i) if (pr[i] > pr[i0]) i0 = i;
        int i1 = (i0 == 0) ? 1 : 0;
        for (int i = 0; i < E_; ++i) if (i != i0 && pr[i] > pr[i1]) i1 = i;
        float s2 = __fadd_rn(pr[i0], pr[i1]);
        wslot[b * 2 + 0] = __fdiv_rn(pr[i0], s2);
        wslot[b * 2 + 1] = __fdiv_rn(pr[i1], s2);
        eslot[b * 2 + 0] = i0;
        eslot[b * 2 + 1] = i1;
    }
}

// ---------------- Kernel 3: split W (fp32) -> Whi/Wlo bf16, fragment layout --
// frag id f = ((e*2+cv)*12 + ksub)*24 + osub ; within frag: [lane][j] (512 ushorts)
// element (lane l, j): o = osub*16 + (l&15), c = ksub*32 + (l>>4)*8 + j
__global__ __launch_bounds__(256) void k_wsplit(const float* __restrict__ W1,
        const float* __restrict__ W2,
        unsigned short* __restrict__ Whif, unsigned short* __restrict__ Wlof) {
    int tid = blockIdx.x * 256 + threadIdx.x;    // 294912 total
    int l = tid & 63;
    int f = tid >> 6;                            // 0..4607
    int osub = f % 24;
    int ksub = (f / 24) % 12;
    int cv = (f / 288) & 1;
    int e = f / 576;
    const float* Wsrc = (cv == 0 ? W1 : W2) + (size_t)e * C_ * C_;
    int o = osub * 16 + (l & 15);
    int c0 = ksub * 32 + (l >> 4) * 8;
    const float* src = Wsrc + (size_t)o * C_ + c0;
    unsigned hw[8], lw[8];
#pragma unroll
    for (int j = 0; j < 8; ++j) {
        float w = src[j];
        unsigned u = __float_as_uint(w);
        unsigned hi = (u + 0x7FFFu + ((u >> 16) & 1u)) >> 16;
        float hf = __uint_as_float(hi << 16);
        float res = __fsub_rn(w, hf);
        unsigned ru = __float_as_uint(res);
        unsigned lo = (ru + 0x7FFFu + ((ru >> 16) & 1u)) >> 16;
        hw[j] = hi & 0xFFFFu;
        lw[j] = lo & 0xFFFFu;
    }
    size_t dst = (size_t)f * 512 + (size_t)l * 8;
    uint4 hv = make_uint4(hw[0] | (hw[1] << 16), hw[2] | (hw[3] << 16),
                          hw[4] | (hw[5] << 16), hw[6] | (hw[7] << 16));
    uint4 lv = make_uint4(lw[0] | (lw[1] << 16), lw[2] | (lw[3] << 16),
                          lw[4] | (lw[5] << 16), lw[6] | (lw[7] << 16));
    *reinterpret_cast<uint4*>(Whif + dst) = hv;
    *reinterpret_cast<uint4*>(Wlof + dst) = lv;
}

// ---------------- conv core: software-pipelined lo/hi MFMA over 12 ksub ------
// sm: byte masks [t][pl][cbyte] stride 48. base: ushort index of (e,cv) frag set.
__device__ __forceinline__ void conv_mfma(const unsigned short* __restrict__ Whif,
                                          const unsigned short* __restrict__ Wlof,
                                          unsigned base,
                                          const unsigned char* __restrict__ sm,
                                          f32x4 (&acc)[3][4],
                                          int wave, int lane, int q, int pl) {
    const unsigned lane8 = (unsigned)lane * 8u;
    const unsigned wbase = base + (unsigned)(wave * 3) * 512u + lane8;
    FragU c0f, c1f, c2f, n0f, n1f, n2f;
    // preload lo(0)
    c0f.u = *reinterpret_cast<const uint4*>(Wlof + wbase);
    c1f.u = *reinterpret_cast<const uint4*>(Wlof + wbase + 512u);
    c2f.u = *reinterpret_cast<const uint4*>(Wlof + wbase + 1024u);
#pragma unroll 1
    for (int ksub = 0; ksub < 12; ++ksub) {
        unsigned fo = wbase + (unsigned)ksub * 24u * 512u;
        // B masks + expand (VALU only, no LDS gather)
        FragU bf[T_];
#pragma unroll
        for (int t = 0; t < T_; ++t) {
            unsigned mbyte = sm[(t * 16 + pl) * 48 + ksub * 4 + q];
            bf[t] = expand_mask(mbyte);
        }
        // issue hi(ksub) loads before lo MFMAs
        n0f.u = *reinterpret_cast<const uint4*>(Whif + fo);
        n1f.u = *reinterpret_cast<const uint4*>(Whif + fo + 512u);
        n2f.u = *reinterpret_cast<const uint4*>(Whif + fo + 1024u);
        // 12 lo MFMAs
#pragma unroll
        for (int t = 0; t < T_; ++t) {
            acc[0][t] = __builtin_amdgcn_mfma_f32_16x16x32_bf16(c0f.v, bf[t].v, acc[0][t], 0, 0, 0);
            acc[1][t] = __builtin_amdgcn_mfma_f32_16x16x32_bf16(c1f.v, bf[t].v, acc[1][t], 0, 0, 0);
            acc[2][t] = __builtin_amdgcn_mfma_f32_16x16x32_bf16(c2f.v, bf[t].v, acc[2][t], 0, 0, 0);
        }
        // issue lo(ksub+1) loads before hi MFMAs (cur regs now free)
        if (ksub < 11) {
            unsigned fn = fo + 24u * 512u;
            c0f.u = *reinterpret_cast<const uint4*>(Wlof + fn);
            c1f.u = *reinterpret_cast<const uint4*>(Wlof + fn + 512u);
            c2f.u = *reinterpret_cast<const uint4*>(Wlof + fn + 1024u);
        }
        // 12 hi MFMAs
#pragma unroll
        for (int t = 0; t < T_; ++t) {
            acc[0][t] = __builtin_amdgcn_mfma_f32_16x16x32_bf16(n0f.v, bf[t].v, acc[0][t], 0, 0, 0);
            acc[1][t] = __builtin_amdgcn_mfma_f32_16x16x32_bf16(n1f.v, bf[t].v, acc[1][t], 0, 0, 0);
            acc[2][t] = __builtin_amdgcn_mfma_f32_16x16x32_bf16(n2f.v, bf[t].v, acc[2][t], 0, 0, 0);
        }
    }
}

// ---------------- Kernel 4: fused MFMA expert -------------------------------
// grid 512 blocks, 512 threads (8 waves). XCD swizzle: all 16 ptiles of a slot
// share blk%8 (same XCD under round-robin dispatch) for weight L2 locality.
__global__ __launch_bounds__(512, 4) void k_expert(
        const float* __restrict__ x,
        const unsigned short* __restrict__ Whif, const unsigned short* __restrict__ Wlof,
        const float* __restrict__ b1, const float* __restrict__ s1sc, const float* __restrict__ s1bi,
        const float* __restrict__ b2, const float* __restrict__ s2sc, const float* __restrict__ s2bi,
        const float* __restrict__ wslot, const int* __restrict__ eslot,
        float* __restrict__ out) {
    int blk = blockIdx.x;
    int slot  = (blk & 7) * 4 + ((blk >> 3) & 3);   // 0..31, constant blk%8 per slot
    int ptile = blk >> 5;                           // 0..15
    int b = slot >> 1;
    int rank = slot & 1;
    int e = eslot[b * 2 + rank];
    float wgt = wslot[b * 2 + rank];
    float tau = tau_of(e);

    __shared__ unsigned char s1m[T_ * 16 * 48];   // [t][pl][cbyte] 8 spikes/byte
    __shared__ unsigned char s2m[T_ * 16 * 48];
    __shared__ float A1s[C_], B1s[C_], BB1s[C_], A2s[C_], B2s[C_], BB2s[C_];

    int tid = threadIdx.x;
    int wave = tid >> 6;
    int lane = tid & 63;
    int q = lane >> 4;
    int pl = lane & 15;
    int p = ptile * 16 + pl;

    float denom = sqrtf(__fadd_rn(1.0f, 1e-5f));
    if (tid < C_) {
        int o = tid;
        A1s[o]  = __fdiv_rn(s1sc[e * C_ + o], denom);
        B1s[o]  = b1[e * C_ + o];
        BB1s[o] = s1bi[e * C_ + o];
        A2s[o]  = __fdiv_rn(s2sc[e * C_ + o], denom);
        B2s[o]  = b2[e * C_ + o];
        BB2s[o] = s2bi[e * C_ + o];
    }

    // ---- LIF1: 8-channel chains -> byte masks in s1m ----
#pragma unroll 1
    for (int task = tid; task < 48 * 16; task += 512) {
        int cb = task >> 4;                 // byte index = c/8
        int tpl = task & 15;
        int tp = ptile * 16 + tpl;
        float v[8];
#pragma unroll
        for (int j = 0; j < 8; ++j) v[j] = 0.0f;
#pragma unroll
        for (int t = 0; t < T_; ++t) {
            int gbase = ((t * B_ + b) * C_ + cb * 8) * HW_ + tp;
            unsigned mb = 0;
#pragma unroll
            for (int j = 0; j < 8; ++j) {
                float xv = x[gbase + j * HW_];
                v[j] = __fadd_rn(v[j], __fdiv_rn(__fsub_rn(xv, v[j]), tau));
                if (__fsub_rn(v[j], 1.0f) >= 0.0f) { mb |= (1u << j); v[j] = 0.0f; }
            }
            s1m[(t * 16 + tpl) * 48 + cb] = (unsigned char)mb;
        }
    }
    __syncthreads();

    const unsigned base_e  = (unsigned)(e * 2) * 12u * 24u * 512u;
    const unsigned base_e2 = base_e + 12u * 24u * 512u;

    // =================== conv1 + epilogue ===================
    {
        f32x4 acc[3][4];
#pragma unroll
        for (int os = 0; os < 3; ++os)
#pragma unroll
            for (int t = 0; t < T_; ++t) acc[os][t] = (f32x4)0.0f;

        conv_mfma(Whif, Wlof, base_e, s1m, acc, wave, lane, q, pl);

        // h = x + bn1(y); out += wgt*h; LIF2 -> s2m bytes (nibble pair via shfl)
#pragma unroll
        for (int os = 0; os < 3; ++os) {
            float v2s[4] = {0.f, 0.f, 0.f, 0.f};
#pragma unroll
            for (int t = 0; t < T_; ++t) {
                unsigned nb = 0;
#pragma unroll
                for (int r = 0; r < 4; ++r) {
                    int o = wave * 48 + os * 16 + q * 4 + r;
                    int gi = ((t * B_ + b) * C_ + o) * HW_ + p;
                    float y = acc[os][t][r];
                    float h = __fadd_rn(x[gi],
                        __fadd_rn(__fmul_rn(__fadd_rn(y, B1s[o]), A1s[o]), BB1s[o]));
                    atomicAdd(&out[gi], wgt * h);
                    v2s[r] = __fadd_rn(v2s[r], __fdiv_rn(__fsub_rn(h, v2s[r]), tau));
                    if (__fsub_rn(v2s[r], 1.0f) >= 0.0f) { nb |= (1u << r); v2s[r] = 0.f; }
                }
                unsigned nb_hi = (unsigned)__shfl_down((int)nb, 16);
                if ((q & 1) == 0) {
                    int cbyte = wave * 6 + os * 2 + (q >> 1);
                    s2m[(t * 16 + pl) * 48 + cbyte] = (unsigned char)(nb | (nb_hi << 4));
                }
            }
        }
    }
    __syncthreads();

    // =================== conv2 + epilogue ===================
    {
        f32x4 acc[3][4];
#pragma unroll
        for (int os = 0; os < 3; ++os)
#pragma unroll
            for (int t = 0; t < T_; ++t) acc[os][t] = (f32x4)0.0f;

        conv_mfma(Whif, Wlof, base_e2, s2m, acc, wave, lane, q, pl);

#pragma unroll
        for (int os = 0; os < 3; ++os) {
#pragma unroll
            for (int t = 0; t < T_; ++t) {
#pragma unroll
                for (int r = 0; r < 4; ++r) {
                    int o = wave * 48 + os * 16 + q * 4 + r;
                    int gi = ((t * B_ + b) * C_ + o) * HW_ + p;
                    float y = acc[os][t][r];
                    float val = wgt * __fadd_rn(__fmul_rn(__fadd_rn(y, B2s[o]), A2s[o]), BB2s[o]);
                    atomicAdd(&out[gi], val);
                }
            }
        }
    }
}

extern "C" void kernel_launch(void* const* d_in, const int* in_sizes, int n_in,
                              void* d_out, int out_size, void* d_ws, size_t ws_size,
                              hipStream_t stream) {
    const float* x    = (const float*)d_in[0];
    const float* rW   = (const float*)d_in[1];
    const float* rb   = (const float*)d_in[2];
    const float* rbs  = (const float*)d_in[3];
    const float* rbb  = (const float*)d_in[4];
    const float* W1   = (const float*)d_in[5];
    const float* b1   = (const float*)d_in[6];
    const float* s1sc = (const float*)d_in[7];
    const float* s1bi = (const float*)d_in[8];
    const float* W2   = (const float*)d_in[9];
    const float* b2   = (const float*)d_in[10];
    const float* s2sc = (const float*)d_in[11];
    const float* s2bi = (const float*)d_in[12];
    float* out = (float*)d_out;

    // ws layout: Whif (4718592 B) | Wlof (4718592 B) | wslot(32f) | eslot(32i) | m(24576f)
    unsigned short* Whif = (unsigned short*)d_ws;
    unsigned short* Wlof = Whif + 2359296;
    float* tail  = (float*)((char*)d_ws + 9437184);
    float* wslot = tail;
    int*   eslot = (int*)(tail + 32);
    float* m     = tail + 64;

    hipLaunchKernelGGL(k_wsplit, dim3(1152), dim3(256), 0, stream, W1, W2, Whif, Wlof);
    hipLaunchKernelGGL(k_router_lif, dim3(B_ * C_), dim3(256), 0, stream, x, m, (float4*)out);
    hipLaunchKernelGGL(k_router_route, dim3(B_), dim3(64), 0, stream,
                       m, rW, rb, rbs, rbb, wslot, eslot);
    hipLaunchKernelGGL(k_expert, dim3(512), dim3(512), 0, stream,
                       x, Whif, Wlof, b1, s1sc, s1bi, b2, s2sc, s2bi, wslot, eslot, out);
}

// Round 5
// 164.039 us; speedup vs baseline: 3.7060x; 1.3162x over previous
//
#include <hip/hip_runtime.h>
#include <math.h>

#define T_  4
#define B_  16
#define C_  384
#define HW_ 256
#define E_  8

typedef __attribute__((ext_vector_type(8))) __bf16 bf16x8;
typedef __attribute__((ext_vector_type(4))) float f32x4;

union FragU { uint4 u; bf16x8 v; };

// taus = jnp.linspace(1.5, 4.0, 8) in fp32, endpoint exact
__device__ __forceinline__ float tau_of(int e) {
    if (e == 7) return 4.0f;
    const float delta = 2.5f / 7.0f;
    return __fadd_rn(1.5f, __fmul_rn((float)e, delta));
}

// bits of m (8 spikes) -> bf16x8 {0,1} fragment
__device__ __forceinline__ FragU expand_mask(unsigned m) {
    FragU f;
    f.u.x = ((m & 1u)   ? 0x3F80u : 0u) | ((m & 2u)   ? 0x3F800000u : 0u);
    f.u.y = ((m & 4u)   ? 0x3F80u : 0u) | ((m & 8u)   ? 0x3F800000u : 0u);
    f.u.z = ((m & 16u)  ? 0x3F80u : 0u) | ((m & 32u)  ? 0x3F800000u : 0u);
    f.u.w = ((m & 64u)  ? 0x3F80u : 0u) | ((m & 128u) ? 0x3F800000u : 0u);
    return f;
}

// ---------------- k_prep: fused weight-split + router LIF -------------------
// blocks [0,1152): W split into Whi/Wlo bf16 fragment layout.
//   frag f = ((e*2+cv)*12 + ksub)*24 + osub; element (lane l, j):
//   o = osub*16 + (l&15), c = ksub*32 + (l>>4)*8 + j
// blocks [1152,7296): router LIF (tau=2), m[t][b][c] = spike-popcount/256 (exact)
__global__ __launch_bounds__(256) void k_prep(const float* __restrict__ x,
        const float* __restrict__ W1, const float* __restrict__ W2,
        unsigned short* __restrict__ Whif, unsigned short* __restrict__ Wlof,
        float* __restrict__ m) {
    if (blockIdx.x < 1152) {
        int tid = blockIdx.x * 256 + threadIdx.x;    // 294912 total
        int l = tid & 63;
        int f = tid >> 6;                            // 0..4607
        int osub = f % 24;
        int ksub = (f / 24) % 12;
        int cv = (f / 288) & 1;
        int e = f / 576;
        const float* Wsrc = (cv == 0 ? W1 : W2) + (size_t)e * C_ * C_;
        int o = osub * 16 + (l & 15);
        int c0 = ksub * 32 + (l >> 4) * 8;
        const float* src = Wsrc + (size_t)o * C_ + c0;
        unsigned hw[8], lw[8];
#pragma unroll
        for (int j = 0; j < 8; ++j) {
            float w = src[j];
            unsigned u = __float_as_uint(w);
            unsigned hi = (u + 0x7FFFu + ((u >> 16) & 1u)) >> 16;
            float hf = __uint_as_float(hi << 16);
            float res = __fsub_rn(w, hf);
            unsigned ru = __float_as_uint(res);
            unsigned lo = (ru + 0x7FFFu + ((ru >> 16) & 1u)) >> 16;
            hw[j] = hi & 0xFFFFu;
            lw[j] = lo & 0xFFFFu;
        }
        size_t dst = (size_t)f * 512 + (size_t)l * 8;
        uint4 hv = make_uint4(hw[0] | (hw[1] << 16), hw[2] | (hw[3] << 16),
                              hw[4] | (hw[5] << 16), hw[6] | (hw[7] << 16));
        uint4 lv = make_uint4(lw[0] | (lw[1] << 16), lw[2] | (lw[3] << 16),
                              lw[4] | (lw[5] << 16), lw[6] | (lw[7] << 16));
        *reinterpret_cast<uint4*>(Whif + dst) = hv;
        *reinterpret_cast<uint4*>(Wlof + dst) = lv;
    } else {
        int bc = blockIdx.x - 1152;
        int b = bc / C_, c = bc % C_;
        int p = threadIdx.x;
        int wv = threadIdx.x >> 6;
        __shared__ int cnt[T_][4];
        float v = 0.0f;
#pragma unroll
        for (int t = 0; t < T_; ++t) {
            float xv = x[((t * B_ + b) * C_ + c) * HW_ + p];
            v = __fadd_rn(v, __fdiv_rn(__fsub_rn(xv, v), 2.0f));
            bool s = (__fsub_rn(v, 1.0f) >= 0.0f);
            if (s) v = 0.0f;
            unsigned long long mask = __ballot(s);
            if ((threadIdx.x & 63) == 0) cnt[t][wv] = (int)__popcll(mask);
        }
        __syncthreads();
        if (threadIdx.x < T_) {
            int t = threadIdx.x;
            int tot = cnt[t][0] + cnt[t][1] + cnt[t][2] + cnt[t][3];
            m[(t * B_ + b) * C_ + c] = (float)tot * 0.00390625f;
        }
    }
}

// ---------------- conv core: software-pipelined lo/hi MFMA over 12 ksub ------
__device__ __forceinline__ void conv_mfma(const unsigned short* __restrict__ Whif,
                                          const unsigned short* __restrict__ Wlof,
                                          unsigned base,
                                          const unsigned char* __restrict__ sm,
                                          f32x4 (&acc)[3][4],
                                          int wave, int lane, int q, int pl) {
    const unsigned lane8 = (unsigned)lane * 8u;
    const unsigned wbase = base + (unsigned)(wave * 3) * 512u + lane8;
    FragU c0f, c1f, c2f, n0f, n1f, n2f;
    c0f.u = *reinterpret_cast<const uint4*>(Wlof + wbase);
    c1f.u = *reinterpret_cast<const uint4*>(Wlof + wbase + 512u);
    c2f.u = *reinterpret_cast<const uint4*>(Wlof + wbase + 1024u);
#pragma unroll 1
    for (int ksub = 0; ksub < 12; ++ksub) {
        unsigned fo = wbase + (unsigned)ksub * 24u * 512u;
        FragU bf[T_];
#pragma unroll
        for (int t = 0; t < T_; ++t) {
            unsigned mbyte = sm[(t * 16 + pl) * 48 + ksub * 4 + q];
            bf[t] = expand_mask(mbyte);
        }
        n0f.u = *reinterpret_cast<const uint4*>(Whif + fo);
        n1f.u = *reinterpret_cast<const uint4*>(Whif + fo + 512u);
        n2f.u = *reinterpret_cast<const uint4*>(Whif + fo + 1024u);
#pragma unroll
        for (int t = 0; t < T_; ++t) {
            acc[0][t] = __builtin_amdgcn_mfma_f32_16x16x32_bf16(c0f.v, bf[t].v, acc[0][t], 0, 0, 0);
            acc[1][t] = __builtin_amdgcn_mfma_f32_16x16x32_bf16(c1f.v, bf[t].v, acc[1][t], 0, 0, 0);
            acc[2][t] = __builtin_amdgcn_mfma_f32_16x16x32_bf16(c2f.v, bf[t].v, acc[2][t], 0, 0, 0);
        }
        if (ksub < 11) {
            unsigned fn = fo + 24u * 512u;
            c0f.u = *reinterpret_cast<const uint4*>(Wlof + fn);
            c1f.u = *reinterpret_cast<const uint4*>(Wlof + fn + 512u);
            c2f.u = *reinterpret_cast<const uint4*>(Wlof + fn + 1024u);
        }
#pragma unroll
        for (int t = 0; t < T_; ++t) {
            acc[0][t] = __builtin_amdgcn_mfma_f32_16x16x32_bf16(n0f.v, bf[t].v, acc[0][t], 0, 0, 0);
            acc[1][t] = __builtin_amdgcn_mfma_f32_16x16x32_bf16(n1f.v, bf[t].v, acc[1][t], 0, 0, 0);
            acc[2][t] = __builtin_amdgcn_mfma_f32_16x16x32_bf16(n2f.v, bf[t].v, acc[2][t], 0, 0, 0);
        }
    }
}

// ---------------- k_expert: rank-paired fused MoE block ---------------------
// grid 256 blocks (b x ptile), 512 threads (8 waves). blk%8 == b%8 (XCD局ity).
// Block computes BOTH top-2 experts for its (b, ptile) -> unique writer, no atomics.
__global__ __launch_bounds__(512, 2) void k_expert(
        const float* __restrict__ x, const float* __restrict__ m,
        const float* __restrict__ rW, const float* __restrict__ rb,
        const float* __restrict__ rbs, const float* __restrict__ rbb,
        const unsigned short* __restrict__ Whif, const unsigned short* __restrict__ Wlof,
        const float* __restrict__ b1, const float* __restrict__ s1sc, const float* __restrict__ s1bi,
        const float* __restrict__ b2, const float* __restrict__ s2sc, const float* __restrict__ s2bi,
        float* __restrict__ out) {
    int blk = blockIdx.x;
    int b = (blk & 7) | (((blk >> 3) & 1) << 3);
    int ptile = blk >> 4;

    __shared__ unsigned char s1m[2][T_ * 16 * 48];
    __shared__ unsigned char s2m[2][T_ * 16 * 48];
    __shared__ float bns[2 * 6 * C_];    // [rank][A1,B1,BB1,A2,B2,BB2][o]
    __shared__ float lg[E_];
    __shared__ float wsl[2];
    __shared__ int esl[2];

    int tid = threadIdx.x;
    int wave = tid >> 6;
    int lane = tid & 63;
    int q = lane >> 4;
    int pl = lane & 15;
    int p = ptile * 16 + pl;
    float denom = sqrtf(__fadd_rn(1.0f, 1e-5f));

    // ---- inline route (wave 0), identical arithmetic to the old k_router_route
    if (tid < 64) {
        int combo = tid & 31, half = tid >> 5;
        int e = combo >> 2, t = combo & 3;
        float dot = 0.0f;
        int c0 = half * 192;
        for (int c = 0; c < 192; ++c)
            dot = fmaf(rW[e * C_ + c0 + c], m[(t * B_ + b) * C_ + c0 + c], dot);
        dot += __shfl_down(dot, 32);
        float Ar = __fdiv_rn(rbs[e], denom);
        float lt = __fadd_rn(__fmul_rn(__fadd_rn(dot, rb[e]), Ar), rbb[e]);
        lt = __fadd_rn(lt, __shfl_xor(lt, 1));
        lt = __fadd_rn(lt, __shfl_xor(lt, 2));
        if (half == 0 && t == 0) lg[e] = __fmul_rn(lt, 0.25f);
    }
    __syncthreads();
    if (tid == 0) {
        float pr[E_];
        float mx = lg[0];
        for (int i = 1; i < E_; ++i) mx = fmaxf(mx, lg[i]);
        float s = 0.0f;
        for (int i = 0; i < E_; ++i) { pr[i] = expf(__fsub_rn(lg[i], mx)); s = __fadd_rn(s, pr[i]); }
        for (int i = 0; i < E_; ++i) pr[i] = __fdiv_rn(pr[i], s);
        int i0 = 0;
        for (int i = 1; i < E_; ++i) if (pr[i] > pr[i0]) i0 = i;
        int i1 = (i0 == 0) ? 1 : 0;
        for (int i = 0; i < E_; ++i) if (i != i0 && pr[i] > pr[i1]) i1 = i;
        float s2 = __fadd_rn(pr[i0], pr[i1]);
        wsl[0] = __fdiv_rn(pr[i0], s2);
        wsl[1] = __fdiv_rn(pr[i1], s2);
        esl[0] = i0;
        esl[1] = i1;
    }
    __syncthreads();

    int e0 = esl[0], e1 = esl[1];
    float tau0 = tau_of(e0), tau1 = tau_of(e1);

    // ---- BN staging for both ranks
    if (tid < C_) {
#pragma unroll
        for (int r_ = 0; r_ < 2; ++r_) {
            int er = (r_ == 0) ? e0 : e1;
            bns[(r_ * 6 + 0) * C_ + tid] = __fdiv_rn(s1sc[er * C_ + tid], denom);
            bns[(r_ * 6 + 1) * C_ + tid] = b1[er * C_ + tid];
            bns[(r_ * 6 + 2) * C_ + tid] = s1bi[er * C_ + tid];
            bns[(r_ * 6 + 3) * C_ + tid] = __fdiv_rn(s2sc[er * C_ + tid], denom);
            bns[(r_ * 6 + 4) * C_ + tid] = b2[er * C_ + tid];
            bns[(r_ * 6 + 5) * C_ + tid] = s2bi[er * C_ + tid];
        }
    }

    // ---- LIF1 for both taus (x loaded once) -> byte masks
#pragma unroll 1
    for (int task = tid; task < 48 * 16; task += 512) {
        int cb = task >> 4;
        int tpl = task & 15;
        int tp = ptile * 16 + tpl;
        float va[8], vb[8];
#pragma unroll
        for (int j = 0; j < 8; ++j) { va[j] = 0.0f; vb[j] = 0.0f; }
#pragma unroll
        for (int t = 0; t < T_; ++t) {
            int gbase = ((t * B_ + b) * C_ + cb * 8) * HW_ + tp;
            unsigned mb0 = 0, mb1 = 0;
#pragma unroll
            for (int j = 0; j < 8; ++j) {
                float xv = x[gbase + j * HW_];
                va[j] = __fadd_rn(va[j], __fdiv_rn(__fsub_rn(xv, va[j]), tau0));
                if (__fsub_rn(va[j], 1.0f) >= 0.0f) { mb0 |= (1u << j); va[j] = 0.0f; }
                vb[j] = __fadd_rn(vb[j], __fdiv_rn(__fsub_rn(xv, vb[j]), tau1));
                if (__fsub_rn(vb[j], 1.0f) >= 0.0f) { mb1 |= (1u << j); vb[j] = 0.0f; }
            }
            s1m[0][(t * 16 + tpl) * 48 + cb] = (unsigned char)mb0;
            s1m[1][(t * 16 + tpl) * 48 + cb] = (unsigned char)mb1;
        }
    }
    __syncthreads();

    float part[3][4][4];
#pragma unroll
    for (int os = 0; os < 3; ++os)
#pragma unroll
        for (int t = 0; t < T_; ++t)
#pragma unroll
            for (int r = 0; r < 4; ++r) part[os][t][r] = 0.0f;

    // ---- conv1 passes (rank 0, rank 1): h = x + bn1(y); part += w*h; LIF2->s2m
#pragma unroll 1
    for (int r_ = 0; r_ < 2; ++r_) {
        int er = (r_ == 0) ? e0 : e1;
        float wr = wsl[r_];
        float taur = (r_ == 0) ? tau0 : tau1;
        unsigned base1 = (unsigned)(er * 2) * 12u * 24u * 512u;

        f32x4 acc[3][4];
#pragma unroll
        for (int os = 0; os < 3; ++os)
#pragma unroll
            for (int t = 0; t < T_; ++t) acc[os][t] = (f32x4)0.0f;

        conv_mfma(Whif, Wlof, base1, &s1m[r_][0], acc, wave, lane, q, pl);

#pragma unroll
        for (int os = 0; os < 3; ++os) {
            float v2s[4] = {0.f, 0.f, 0.f, 0.f};
#pragma unroll
            for (int t = 0; t < T_; ++t) {
                unsigned nb = 0;
#pragma unroll
                for (int r = 0; r < 4; ++r) {
                    int o = wave * 48 + os * 16 + q * 4 + r;
                    int gi = ((t * B_ + b) * C_ + o) * HW_ + p;
                    float y = acc[os][t][r];
                    float h = __fadd_rn(x[gi],
                        __fadd_rn(__fmul_rn(__fadd_rn(y, bns[(r_ * 6 + 1) * C_ + o]),
                                            bns[(r_ * 6 + 0) * C_ + o]),
                                  bns[(r_ * 6 + 2) * C_ + o]));
                    part[os][t][r] = fmaf(wr, h, part[os][t][r]);
                    v2s[r] = __fadd_rn(v2s[r], __fdiv_rn(__fsub_rn(h, v2s[r]), taur));
                    if (__fsub_rn(v2s[r], 1.0f) >= 0.0f) { nb |= (1u << r); v2s[r] = 0.f; }
                }
                unsigned nb_hi = (unsigned)__shfl_down((int)nb, 16);
                if ((q & 1) == 0) {
                    int cbyte = wave * 6 + os * 2 + (q >> 1);
                    s2m[r_][(t * 16 + pl) * 48 + cbyte] = (unsigned char)(nb | (nb_hi << 4));
                }
            }
        }
    }
    __syncthreads();

    // ---- conv2 passes (rank 0, rank 1): part += w*bn2(y)
#pragma unroll 1
    for (int r_ = 0; r_ < 2; ++r_) {
        int er = (r_ == 0) ? e0 : e1;
        float wr = wsl[r_];
        unsigned base2 = (unsigned)(er * 2 + 1) * 12u * 24u * 512u;

        f32x4 acc[3][4];
#pragma unroll
        for (int os = 0; os < 3; ++os)
#pragma unroll
            for (int t = 0; t < T_; ++t) acc[os][t] = (f32x4)0.0f;

        conv_mfma(Whif, Wlof, base2, &s2m[r_][0], acc, wave, lane, q, pl);

#pragma unroll
        for (int os = 0; os < 3; ++os)
#pragma unroll
            for (int t = 0; t < T_; ++t)
#pragma unroll
                for (int r = 0; r < 4; ++r) {
                    int o = wave * 48 + os * 16 + q * 4 + r;
                    float y = acc[os][t][r];
                    float val = __fadd_rn(__fmul_rn(__fadd_rn(y, bns[(r_ * 6 + 4) * C_ + o]),
                                                    bns[(r_ * 6 + 3) * C_ + o]),
                                          bns[(r_ * 6 + 5) * C_ + o]);
                    part[os][t][r] = fmaf(wr, val, part[os][t][r]);
                }
    }

    // ---- unique-writer store
#pragma unroll
    for (int os = 0; os < 3; ++os)
#pragma unroll
        for (int t = 0; t < T_; ++t)
#pragma unroll
            for (int r = 0; r < 4; ++r) {
                int o = wave * 48 + os * 16 + q * 4 + r;
                int gi = ((t * B_ + b) * C_ + o) * HW_ + p;
                out[gi] = part[os][t][r];
            }
}

extern "C" void kernel_launch(void* const* d_in, const int* in_sizes, int n_in,
                              void* d_out, int out_size, void* d_ws, size_t ws_size,
                              hipStream_t stream) {
    const float* x    = (const float*)d_in[0];
    const float* rW   = (const float*)d_in[1];
    const float* rb   = (const float*)d_in[2];
    const float* rbs  = (const float*)d_in[3];
    const float* rbb  = (const float*)d_in[4];
    const float* W1   = (const float*)d_in[5];
    const float* b1   = (const float*)d_in[6];
    const float* s1sc = (const float*)d_in[7];
    const float* s1bi = (const float*)d_in[8];
    const float* W2   = (const float*)d_in[9];
    const float* b2   = (const float*)d_in[10];
    const float* s2sc = (const float*)d_in[11];
    const float* s2bi = (const float*)d_in[12];
    float* out = (float*)d_out;

    // ws layout: Whif (4718592 B) | Wlof (4718592 B) | m (24576 floats)
    unsigned short* Whif = (unsigned short*)d_ws;
    unsigned short* Wlof = Whif + 2359296;
    float* m = (float*)((char*)d_ws + 9437184);

    hipLaunchKernelGGL(k_prep, dim3(1152 + B_ * C_), dim3(256), 0, stream,
                       x, W1, W2, Whif, Wlof, m);
    hipLaunchKernelGGL(k_expert, dim3(256), dim3(512), 0, stream,
                       x, m, rW, rb, rbs, rbb, Whif, Wlof,
                       b1, s1sc, s1bi, b2, s2sc, s2bi, out);
}